// Round 1
// baseline (506.509 us; speedup 1.0000x reference)
//
#include <hip/hip_runtime.h>

// ---------------- types & helpers ----------------
typedef __bf16 bf16x8 __attribute__((ext_vector_type(8)));
typedef float f32x4 __attribute__((ext_vector_type(4)));

#define DEV __device__ __forceinline__

DEV float bf2f(unsigned short u) {
  union { unsigned int i; float f; } c; c.i = ((unsigned int)u) << 16; return c.f;
}
DEV unsigned short f2bf(float f) {
  union { float f; unsigned int i; } c; c.f = f;
  return (unsigned short)((c.i + 0x7FFFu + ((c.i >> 16) & 1u)) >> 16);
}

union FragU { bf16x8 v; unsigned short u[8]; };

DEV void gld_lds16(const void* g, void* l) {
  __builtin_amdgcn_global_load_lds((const __attribute__((address_space(1))) void*)g,
                                   (__attribute__((address_space(3))) void*)l, 16, 0, 0);
}

#define MFMA(a, b, c) __builtin_amdgcn_mfma_f32_16x16x32_bf16((a), (b), (c), 0, 0, 0)

// ---------------- problem constants ----------------
#define BB 8
#define NN 1569
#define DD 768
#define HH 12
#define DH 64
#define FF 8
#define NFR 196
#define NTT 77
#define DT_ 512
#define MROWS 12552   // B*N
#define MTEXT 616     // B*NT

// ---------------- fp32 -> bf16 convert ----------------
__global__ void cvt_f32_bf16(const float* __restrict__ in, unsigned short* __restrict__ out, int n4) {
  int i = blockIdx.x * blockDim.x + threadIdx.x;
  int stride = gridDim.x * blockDim.x;
  for (; i < n4; i += stride) {
    float4 v = ((const float4*)in)[i];
    ushort4 o;
    o.x = f2bf(v.x); o.y = f2bf(v.y); o.z = f2bf(v.z); o.w = f2bf(v.w);
    ((ushort4*)out)[i] = o;
  }
}

// ---------------- transpose + convert: out[C][R] = in[R][C] ----------------
__global__ __launch_bounds__(256) void transpose_cvt(const float* __restrict__ in,
                                                     unsigned short* __restrict__ out,
                                                     int R, int C) {
  __shared__ float tile[32][33];
  int bx = blockIdx.x * 32;   // C base
  int by = blockIdx.y * 32;   // R base
  int tx = threadIdx.x & 31;
  int ty0 = threadIdx.x >> 5; // 0..7
  for (int dy = 0; dy < 32; dy += 8) {
    int r = by + ty0 + dy, c = bx + tx;
    tile[ty0 + dy][tx] = (r < R && c < C) ? in[(size_t)r * C + c] : 0.f;
  }
  __syncthreads();
  for (int dy = 0; dy < 32; dy += 8) {
    int orow = bx + ty0 + dy;  // C index
    int ocol = by + tx;        // R index
    if (orow < C && ocol < R) out[(size_t)orow * R + ocol] = f2bf(tile[tx][ty0 + dy]);
  }
}

// ---------------- GEMM: C[M,Ncols] = A[M,K] @ Bt[Ncols,K]^T, templated epilogue ----------------
enum { EPI_QKV = 0, EPI_XOUT = 1, EPI_QI = 2, EPI_KVT = 3, EPI_FINAL = 4 };

struct EpiParams {
  float* outf;
  unsigned short *o0, *o1, *o2;
  const float *bias, *aux, *alphap;
};

template <int EPI>
__global__ __launch_bounds__(256)
void gemm_bt(const unsigned short* __restrict__ A, const unsigned short* __restrict__ Bt,
             int M, int K, EpiParams ep) {
  __shared__ __align__(16) unsigned short lA[128 * 32];
  __shared__ __align__(16) unsigned short lB[128 * 32];
  const int brow = blockIdx.y * 128, bcol = blockIdx.x * 128;
  const int t = threadIdx.x, wave = t >> 6, lane = t & 63, g = lane >> 4, l15 = lane & 15;
  const int wr = wave >> 1, wc = wave & 1;

  f32x4 acc[4][4];
#pragma unroll
  for (int i = 0; i < 4; ++i)
#pragma unroll
    for (int j = 0; j < 4; ++j) acc[i][j] = {0.f, 0.f, 0.f, 0.f};

  const int nk = K >> 5;
  for (int kt = 0; kt < nk; ++kt) {
    const int k0 = kt << 5;
    // stage A,B tiles: linear LDS dest, XOR-swizzled global source (granule ^= (row>>1)&3)
#pragma unroll
    for (int c = 0; c < 2; ++c) {
      int sb = wave * 1024 + c * 512;      // element base (wave-uniform)
      int slot = sb + lane * 8;            // this lane's element slot
      int row = slot >> 5;
      int gl = (slot >> 3) & 3;
      int swz = gl ^ ((row >> 1) & 3);
      int ra = brow + row; if (ra > M - 1) ra = M - 1;
      gld_lds16(A + (size_t)ra * K + k0 + swz * 8, &lA[sb]);
      int rb = bcol + row;                  // Ncols always multiple of 128
      gld_lds16(Bt + (size_t)rb * K + k0 + swz * 8, &lB[sb]);
    }
    __syncthreads();
    FragU af[4], bf[4];
#pragma unroll
    for (int i = 0; i < 4; ++i) {
      int rowa = wr * 64 + i * 16 + l15;
      int swa = g ^ ((rowa >> 1) & 3);
      af[i].v = *(const bf16x8*)(&lA[rowa * 32 + swa * 8]);
      int rowb = wc * 64 + i * 16 + l15;
      int swb = g ^ ((rowb >> 1) & 3);
      bf[i].v = *(const bf16x8*)(&lB[rowb * 32 + swb * 8]);
    }
#pragma unroll
    for (int i = 0; i < 4; ++i)
#pragma unroll
      for (int j = 0; j < 4; ++j)
        acc[i][j] = MFMA(af[i].v, bf[j].v, acc[i][j]);
    __syncthreads();
  }

  // epilogue: D row = (lane>>4)*4+reg, col = lane&15 (m89-verified)
#pragma unroll
  for (int i = 0; i < 4; ++i) {
#pragma unroll
    for (int r = 0; r < 4; ++r) {
      int mrow = brow + wr * 64 + i * 16 + g * 4 + r;
      if (mrow >= M) continue;
      int bidx = 0, nn = 0, tt = 0;
      if constexpr (EPI == EPI_QKV || EPI == EPI_QI) { bidx = mrow / NN; nn = mrow - bidx * NN; }
      if constexpr (EPI == EPI_KVT) { bidx = mrow / NTT; tt = mrow - bidx * NTT; }
#pragma unroll
      for (int j = 0; j < 4; ++j) {
        int col = bcol + wc * 64 + j * 16 + l15;
        float val = acc[i][j][r];
        if constexpr (EPI == EPI_XOUT) {
          ep.outf[(size_t)mrow * DD + col] = val + ep.bias[col];
        } else if constexpr (EPI == EPI_FINAL) {
          size_t o = (size_t)mrow * DD + col;
          ep.outf[o] = ep.aux[o] + ep.alphap[0] * (val + ep.bias[col]);
        } else if constexpr (EPI == EPI_QKV) {
          int which = col / DD; int within = col - which * DD;
          int h = within >> 6, dd2 = within & 63;
          size_t dst = (((size_t)bidx * HH + h) * NN + nn) * DH + dd2;
          if (which == 0) ep.o0[dst] = f2bf(val * 0.125f);
          else if (which == 1) ep.o1[dst] = f2bf(val);
          else ep.o2[dst] = f2bf(val);
        } else if constexpr (EPI == EPI_QI) {
          int h = col >> 6, dd2 = col & 63;
          ep.o0[(((size_t)bidx * HH + h) * NN + nn) * DH + dd2] = f2bf(val * 0.125f);
        } else if constexpr (EPI == EPI_KVT) {
          int kvi = col / DD; int within = col - kvi * DD;
          int h = within >> 6, dd2 = within & 63;
          size_t dst = (((size_t)bidx * HH + h) * NTT + tt) * DH + dd2;
          if (kvi == 0) ep.o0[dst] = f2bf(val);
          else ep.o1[dst] = f2bf(val);
        }
      }
    }
  }
}

// ---------------- CLS attention: 1 query x 1569 keys per (b,h) ----------------
__global__ __launch_bounds__(256)
void cls_attn(const unsigned short* __restrict__ qg, const unsigned short* __restrict__ kg,
              const unsigned short* __restrict__ vg, unsigned short* __restrict__ outg) {
  __shared__ float q0[64];
  __shared__ float sc[NN];
  __shared__ float red[256];
  __shared__ float opart[4][64];
  const int bh = blockIdx.x, b = bh / HH, h = bh - b * HH;
  const int t = threadIdx.x;
  const size_t base = (size_t)bh * NN * DH;
  if (t < 64) q0[t] = bf2f(qg[base + t]);
  __syncthreads();
  for (int j = t; j < NN; j += 256) {
    const unsigned short* kr = kg + base + (size_t)j * DH;
    float s = 0.f;
#pragma unroll
    for (int dd = 0; dd < 64; dd += 8) {
      float4 raw = *(const float4*)(kr + dd);
      const unsigned short* pu = (const unsigned short*)&raw;
#pragma unroll
      for (int z = 0; z < 8; ++z) s += q0[dd + z] * bf2f(pu[z]);
    }
    sc[j] = s;
  }
  __syncthreads();
  float lm = -1e30f;
  for (int j = t; j < NN; j += 256) lm = fmaxf(lm, sc[j]);
  red[t] = lm; __syncthreads();
  for (int off = 128; off > 0; off >>= 1) { if (t < off) red[t] = fmaxf(red[t], red[t + off]); __syncthreads(); }
  float m = red[0];
  __syncthreads();
  float ls = 0.f;
  for (int j = t; j < NN; j += 256) { float p = __expf(sc[j] - m); sc[j] = p; ls += p; }
  __syncthreads();
  red[t] = ls; __syncthreads();
  for (int off = 128; off > 0; off >>= 1) { if (t < off) red[t] += red[t + off]; __syncthreads(); }
  float invS = 1.f / red[0];
  int dd = t & 63, part = t >> 6;
  float o = 0.f;
  for (int j = part; j < NN; j += 4) o += sc[j] * bf2f(vg[base + (size_t)j * DH + dd]);
  opart[part][dd] = o;
  __syncthreads();
  if (t < 64) {
    float r = (opart[0][t] + opart[1][t] + opart[2][t] + opart[3][t]) * invS;
    outg[((size_t)b * NN) * DD + h * DH + t] = f2bf(r);
  }
}

// ---------------- frame attention: 196q x 197k per (b,h,frame) ----------------
__global__ __launch_bounds__(256)
void frame_attn(const unsigned short* __restrict__ qg, const unsigned short* __restrict__ kg,
                const unsigned short* __restrict__ vg, unsigned short* __restrict__ outg) {
  __shared__ __align__(16) unsigned short lK[224 * 64];   // [key][d], granule ^= key&7
  __shared__ __align__(16) unsigned short lV[64 * 232];   // [d][key] transposed, stride 232
  const int bid = blockIdx.x, bh = bid >> 3, fi = bid & 7;
  const int b = bh / HH, h = bh - b * HH;
  const int t = threadIdx.x, wave = t >> 6, lane = t & 63, g = lane >> 4, l15 = lane & 15;
  const size_t base = (size_t)bh * NN * DH;

#pragma unroll
  for (int c = 0; c < 7; ++c) {  // 224*64 elems = 1792 granules of 8
    int gI = t + 256 * c;
    int elem = gI * 8, row = elem >> 6, gl = (elem >> 3) & 7;
    int srcg = gl ^ (row & 7);
    float4 val;
    if (row < 197) {
      int nrow = (row == 0) ? 0 : (fi * NFR + row);
      val = *(const float4*)(kg + base + (size_t)nrow * DH + srcg * 8);
    } else { val = make_float4(0.f, 0.f, 0.f, 0.f); }
    *(float4*)(&lK[elem]) = val;
  }
  for (int idx = t; idx < 197 * 64; idx += 256) {
    int row = idx >> 6, dd = idx & 63;
    int nrow = (row == 0) ? 0 : (fi * NFR + row);
    lV[dd * 232 + row] = vg[base + (size_t)nrow * DH + dd];
  }
  for (int idx = t; idx < 27 * 64; idx += 256) {
    int row = 197 + (idx >> 6), dd = idx & 63;
    lV[dd * 232 + row] = 0;
  }
  __syncthreads();

  for (int qt = wave; qt < 13; qt += 4) {
    int qr = qt * 16 + l15; if (qr > 195) qr = 195;
    const unsigned short* qp = qg + base + (size_t)(1 + fi * NFR + qr) * DH + g * 8;
    bf16x8 bq0 = *(const bf16x8*)(qp);
    bf16x8 bq1 = *(const bf16x8*)(qp + 32);
    // swapped QK^T: S^T[key][qrow]; lane owns qrow=l15, keys kt*16+g*4+r
    f32x4 s[13];
#pragma unroll
    for (int kt2 = 0; kt2 < 13; ++kt2) {
      int krow = kt2 * 16 + l15;
      int rb = krow * 64;
      int sw0 = (g ^ (krow & 7)) * 8;
      int sw1 = ((4 + g) ^ (krow & 7)) * 8;
      f32x4 a = {0.f, 0.f, 0.f, 0.f};
      a = MFMA(*(const bf16x8*)(&lK[rb + sw0]), bq0, a);
      a = MFMA(*(const bf16x8*)(&lK[rb + sw1]), bq1, a);
      s[kt2] = a;
    }
    float m = -1e30f;
#pragma unroll
    for (int kt2 = 0; kt2 < 13; ++kt2)
#pragma unroll
      for (int r = 0; r < 4; ++r) {
        int key = kt2 * 16 + g * 4 + r;
        if (key >= 197) s[kt2][r] = -1e30f;
        m = fmaxf(m, s[kt2][r]);
      }
    m = fmaxf(m, __shfl_xor(m, 16));
    m = fmaxf(m, __shfl_xor(m, 32));
    float sum = 0.f;
#pragma unroll
    for (int kt2 = 0; kt2 < 13; ++kt2)
#pragma unroll
      for (int r = 0; r < 4; ++r) { float p = __expf(s[kt2][r] - m); s[kt2][r] = p; sum += p; }
    sum += __shfl_xor(sum, 16);
    sum += __shfl_xor(sum, 32);
    float inv = 1.f / sum;
#pragma unroll
    for (int kt2 = 0; kt2 < 13; ++kt2)
#pragma unroll
      for (int r = 0; r < 4; ++r) s[kt2][r] *= inv;
    // PV: A-frag built by cross-lane shuffle of P
    f32x4 o[4];
#pragma unroll
    for (int dt = 0; dt < 4; ++dt) o[dt] = {0.f, 0.f, 0.f, 0.f};
#pragma unroll
    for (int K32 = 0; K32 < 7; ++K32) {
      FragU af;
#pragma unroll
      for (int j = 0; j < 8; ++j) {
        int srcl = l15 + 16 * ((((lane >> 4) & 1) * 8 + j) >> 2);
        float v0 = __shfl(s[2 * K32][j & 3], srcl, 64);
        float v1 = (2 * K32 + 1 < 13) ? __shfl(s[2 * K32 + 1][j & 3], srcl, 64) : 0.f;
        af.u[j] = f2bf((g < 2) ? v0 : v1);
      }
#pragma unroll
      for (int dt = 0; dt < 4; ++dt) {
        const bf16x8 bv = *(const bf16x8*)(&lV[(dt * 16 + l15) * 232 + K32 * 32 + g * 8]);
        o[dt] = MFMA(af.v, bv, o[dt]);
      }
    }
#pragma unroll
    for (int dt = 0; dt < 4; ++dt)
#pragma unroll
      for (int r = 0; r < 4; ++r) {
        int qrow = qt * 16 + g * 4 + r;
        if (qrow < 196) {
          size_t nrow = 1 + (size_t)fi * NFR + qrow;
          outg[((size_t)b * NN + nrow) * DD + h * DH + dt * 16 + l15] = f2bf(o[dt][r]);
        }
      }
  }
}

// ---------------- i2t cross attention: 1569q x 77k per (b,h) ----------------
__global__ __launch_bounds__(256)
void i2t_attn(const unsigned short* __restrict__ qg, const unsigned short* __restrict__ ktg,
              const unsigned short* __restrict__ vtg, const float* __restrict__ mask,
              unsigned short* __restrict__ outg) {
  __shared__ __align__(16) unsigned short lK[80 * 64];
  __shared__ __align__(16) unsigned short lV[64 * 88];
  const int bid = blockIdx.x;
  const int bh = bid % 96, chunk = bid / 96;
  const int b = bh / HH, h = bh - b * HH;
  const int t = threadIdx.x, wave = t >> 6, lane = t & 63, g = lane >> 4, l15 = lane & 15;
  const size_t kvbase = (size_t)bh * NTT * DH;
#pragma unroll
  for (int c = 0; c < 3; ++c) {
    int gI = t + 256 * c;
    if (gI < 640) {
      int elem = gI * 8, row = elem >> 6, gl = (elem >> 3) & 7;
      int srcg = gl ^ (row & 7);
      float4 val = make_float4(0.f, 0.f, 0.f, 0.f);
      if (row < NTT) val = *(const float4*)(ktg + kvbase + (size_t)row * DH + srcg * 8);
      *(float4*)(&lK[elem]) = val;
    }
  }
  for (int idx = t; idx < NTT * 64; idx += 256) {
    int row = idx >> 6, dd = idx & 63;
    lV[dd * 88 + row] = vtg[kvbase + (size_t)row * DH + dd];
  }
  for (int idx = t; idx < 3 * 64; idx += 256) {
    int row = NTT + (idx >> 6), dd = idx & 63;
    lV[dd * 88 + row] = 0;
  }
  __syncthreads();
  const size_t qbase = (size_t)bh * NN * DH;
#pragma unroll
  for (int i4 = 0; i4 < 4; ++i4) {
    int qt = chunk * 16 + i4 * 4 + wave;
    if (qt >= 99) continue;
    int qr = qt * 16 + l15; if (qr > NN - 1) qr = NN - 1;
    const unsigned short* qp = qg + qbase + (size_t)qr * DH + g * 8;
    bf16x8 bq0 = *(const bf16x8*)(qp);
    bf16x8 bq1 = *(const bf16x8*)(qp + 32);
    f32x4 s[5];
#pragma unroll
    for (int kt2 = 0; kt2 < 5; ++kt2) {
      int krow = kt2 * 16 + l15;
      int rb = krow * 64;
      int sw0 = (g ^ (krow & 7)) * 8;
      int sw1 = ((4 + g) ^ (krow & 7)) * 8;
      f32x4 a = {0.f, 0.f, 0.f, 0.f};
      a = MFMA(*(const bf16x8*)(&lK[rb + sw0]), bq0, a);
      a = MFMA(*(const bf16x8*)(&lK[rb + sw1]), bq1, a);
      s[kt2] = a;
    }
    float m = -1e30f;
#pragma unroll
    for (int kt2 = 0; kt2 < 5; ++kt2)
#pragma unroll
      for (int r = 0; r < 4; ++r) {
        int key = kt2 * 16 + g * 4 + r;
        if (key < NTT) s[kt2][r] += mask[b * NTT + key];
        else s[kt2][r] = -1e30f;
        m = fmaxf(m, s[kt2][r]);
      }
    m = fmaxf(m, __shfl_xor(m, 16));
    m = fmaxf(m, __shfl_xor(m, 32));
    float sum = 0.f;
#pragma unroll
    for (int kt2 = 0; kt2 < 5; ++kt2)
#pragma unroll
      for (int r = 0; r < 4; ++r) { float p = __expf(s[kt2][r] - m); s[kt2][r] = p; sum += p; }
    sum += __shfl_xor(sum, 16);
    sum += __shfl_xor(sum, 32);
    float inv = 1.f / sum;
#pragma unroll
    for (int kt2 = 0; kt2 < 5; ++kt2)
#pragma unroll
      for (int r = 0; r < 4; ++r) s[kt2][r] *= inv;
    f32x4 o[4];
#pragma unroll
    for (int dt = 0; dt < 4; ++dt) o[dt] = {0.f, 0.f, 0.f, 0.f};
#pragma unroll
    for (int K32 = 0; K32 < 3; ++K32) {
      FragU af;
#pragma unroll
      for (int j = 0; j < 8; ++j) {
        int srcl = l15 + 16 * ((((lane >> 4) & 1) * 8 + j) >> 2);
        float v0 = __shfl(s[2 * K32][j & 3], srcl, 64);
        float v1 = (2 * K32 + 1 < 5) ? __shfl(s[2 * K32 + 1][j & 3], srcl, 64) : 0.f;
        af.u[j] = f2bf((g < 2) ? v0 : v1);
      }
#pragma unroll
      for (int dt = 0; dt < 4; ++dt) {
        const bf16x8 bv = *(const bf16x8*)(&lV[(dt * 16 + l15) * 88 + K32 * 32 + g * 8]);
        o[dt] = MFMA(af.v, bv, o[dt]);
      }
    }
#pragma unroll
    for (int dt = 0; dt < 4; ++dt)
#pragma unroll
      for (int r = 0; r < 4; ++r) {
        int qrow = qt * 16 + g * 4 + r;
        if (qrow < NN)
          outg[((size_t)b * NN + qrow) * DD + h * DH + dt * 16 + l15] = f2bf(o[dt][r]);
      }
  }
}

// ---------------- LayerNorm: fp32 in -> bf16 out, row = 768 ----------------
__global__ __launch_bounds__(256)
void ln_kernel(const float* __restrict__ x, const float* __restrict__ gam,
               const float* __restrict__ bet, unsigned short* __restrict__ out) {
  __shared__ float red[256];
  const int row = blockIdx.x, t = threadIdx.x;
  const size_t base = (size_t)row * DD;
  float v0 = x[base + t], v1 = x[base + t + 256], v2 = x[base + t + 512];
  red[t] = v0 + v1 + v2; __syncthreads();
  for (int off = 128; off > 0; off >>= 1) { if (t < off) red[t] += red[t + off]; __syncthreads(); }
  float mu = red[0] * (1.f / 768.f);
  __syncthreads();
  float d0 = v0 - mu, d1 = v1 - mu, d2 = v2 - mu;
  red[t] = d0 * d0 + d1 * d1 + d2 * d2; __syncthreads();
  for (int off = 128; off > 0; off >>= 1) { if (t < off) red[t] += red[t + off]; __syncthreads(); }
  float rs = rsqrtf(red[0] * (1.f / 768.f) + 1e-5f);
  out[base + t] = f2bf(d0 * rs * gam[t] + bet[t]);
  out[base + t + 256] = f2bf(d1 * rs * gam[t + 256] + bet[t + 256]);
  out[base + t + 512] = f2bf(d2 * rs * gam[t + 512] + bet[t + 512]);
}

// ---------------- workspace layout ----------------
typedef unsigned short us_t;
static constexpr size_t SZ_WQKVT = (size_t)2304 * 768 * 2;
static constexpr size_t SZ_W768  = (size_t)768 * 768 * 2;
static constexpr size_t SZ_WKVT  = (size_t)1536 * 512 * 2;
static constexpr size_t SZ_XB    = (size_t)MROWS * DD * 2;
static constexpr size_t SZ_YB    = (size_t)MTEXT * DT_ * 2;
static constexpr size_t SZ_KT    = (size_t)96 * NTT * DH * 2;

static constexpr size_t OFF_WQKVT = 0;
static constexpr size_t OFF_WPROJT = OFF_WQKVT + SZ_WQKVT;
static constexpr size_t OFF_WKVT = OFF_WPROJT + SZ_W768;
static constexpr size_t OFF_WQIT = OFF_WKVT + SZ_WKVT;
static constexpr size_t OFF_WPIT = OFF_WQIT + SZ_W768;
static constexpr size_t OFF_XB  = OFF_WPIT + SZ_W768;
static constexpr size_t OFF_YB  = OFF_XB + SZ_XB;
static constexpr size_t OFF_QB  = OFF_YB + SZ_YB;
static constexpr size_t OFF_KB  = OFF_QB + SZ_XB;
static constexpr size_t OFF_VB  = OFF_KB + SZ_XB;
static constexpr size_t OFF_XOUT = OFF_VB + SZ_XB;

extern "C" void kernel_launch(void* const* d_in, const int* in_sizes, int n_in,
                              void* d_out, int out_size, void* d_ws, size_t ws_size,
                              hipStream_t stream) {
  const float* x      = (const float*)d_in[0];
  const float* y      = (const float*)d_in[1];
  const float* y_mask = (const float*)d_in[2];
  // d_in[3] = f (==8), unused
  const float* w_qkv  = (const float*)d_in[4];
  const float* w_proj = (const float*)d_in[5];
  const float* b_proj = (const float*)d_in[6];
  const float* w_kv   = (const float*)d_in[7];
  const float* w_qi   = (const float*)d_in[8];
  const float* w_pi   = (const float*)d_in[9];
  const float* b_pi   = (const float*)d_in[10];
  const float* alpha  = (const float*)d_in[11];
  const float* ln_g   = (const float*)d_in[12];
  const float* ln_b   = (const float*)d_in[13];
  float* out = (float*)d_out;
  char* ws = (char*)d_ws;

  us_t* wqkvT = (us_t*)(ws + OFF_WQKVT);
  us_t* wprojT = (us_t*)(ws + OFF_WPROJT);
  us_t* wkvT = (us_t*)(ws + OFF_WKVT);
  us_t* wqiT = (us_t*)(ws + OFF_WQIT);
  us_t* wpiT = (us_t*)(ws + OFF_WPIT);
  us_t* xb  = (us_t*)(ws + OFF_XB);
  us_t* yb  = (us_t*)(ws + OFF_YB);
  us_t* qb  = (us_t*)(ws + OFF_QB);
  us_t* kb  = (us_t*)(ws + OFF_KB);
  us_t* vb  = (us_t*)(ws + OFF_VB);
  float* xoutf = (float*)(ws + OFF_XOUT);
  // aliases (lifetimes verified: no overlap while live)
  us_t* attn_out = xb;                       // after qkv GEMM consumed xb
  us_t* lnout = qb;                          // after attention consumed q
  us_t* qib = kb;                            // after attention consumed k
  us_t* ktb = vb;                            // after attention consumed v
  us_t* vtb = (us_t*)(ws + OFF_VB + SZ_KT);
  us_t* i2t_out = xb;                        // after proj GEMM consumed attn_out

  // 1) conversions / weight transposes
  cvt_f32_bf16<<<2048, 256, 0, stream>>>(x, xb, MROWS * DD / 4);
  cvt_f32_bf16<<<308, 256, 0, stream>>>(y, yb, MTEXT * DT_ / 4);
  transpose_cvt<<<dim3(72, 24), 256, 0, stream>>>(w_qkv, wqkvT, 768, 2304);
  transpose_cvt<<<dim3(24, 24), 256, 0, stream>>>(w_proj, wprojT, 768, 768);
  transpose_cvt<<<dim3(48, 16), 256, 0, stream>>>(w_kv, wkvT, 512, 1536);
  transpose_cvt<<<dim3(24, 24), 256, 0, stream>>>(w_qi, wqiT, 768, 768);
  transpose_cvt<<<dim3(24, 24), 256, 0, stream>>>(w_pi, wpiT, 768, 768);

  // 2) qkv projection, scatter to [B,H,N,d] with q*0.125
  EpiParams e1{}; e1.o0 = qb; e1.o1 = kb; e1.o2 = vb;
  gemm_bt<EPI_QKV><<<dim3(18, 99), 256, 0, stream>>>(xb, wqkvT, MROWS, 768, e1);

  // 3) attention
  cls_attn<<<96, 256, 0, stream>>>(qb, kb, vb, attn_out);
  frame_attn<<<768, 256, 0, stream>>>(qb, kb, vb, attn_out);

  // 4) out projection + bias -> x_out (fp32)
  EpiParams e2{}; e2.outf = xoutf; e2.bias = b_proj;
  gemm_bt<EPI_XOUT><<<dim3(6, 99), 256, 0, stream>>>(attn_out, wprojT, MROWS, 768, e2);

  // 5) LN -> bf16
  ln_kernel<<<MROWS, 256, 0, stream>>>(xoutf, ln_g, ln_b, lnout);

  // 6) q_i projection (scaled), scatter to [B,H,N,d]
  EpiParams e3{}; e3.o0 = qib;
  gemm_bt<EPI_QI><<<dim3(6, 99), 256, 0, stream>>>(lnout, wqiT, MROWS, 768, e3);

  // 7) text kv projection, scatter to k_t/v_t [B,H,NT,d]
  EpiParams e4{}; e4.o0 = ktb; e4.o1 = vtb;
  gemm_bt<EPI_KVT><<<dim3(12, 5), 256, 0, stream>>>(yb, wkvT, MTEXT, 512, e4);

  // 8) i2t cross attention
  i2t_attn<<<dim3(96 * 7), 256, 0, stream>>>(qib, ktb, vtb, y_mask, i2t_out);

  // 9) final projection + bias, fused d_out = x_out + alpha*yo
  EpiParams e5{}; e5.outf = out; e5.bias = b_pi; e5.aux = xoutf; e5.alphap = alpha;
  gemm_bt<EPI_FINAL><<<dim3(6, 99), 256, 0, stream>>>(i2t_out, wpiT, MROWS, 768, e5);
}